// Round 15
// baseline (3426.458 us; speedup 1.0000x reference)
//
#include <hip/hip_runtime.h>

#define SLEN 512
#define BATCH 64
#define HID 256
#define EMB 128
#define NT 18
#define NCHAIN 128        // 2 dirs x 64 batches
#define FB 8              // batches per feats block
#define SB 16             // timesteps per feats block

typedef unsigned int u32;

__device__ __forceinline__ float sigmoidf_(float v) { return 1.0f / (1.0f + expf(-v)); }
__device__ __forceinline__ u32 aload(const u32* p) {
  return __hip_atomic_load((u32*)p, __ATOMIC_RELAXED, __HIP_MEMORY_SCOPE_AGENT);
}
// LDS-only barrier: drains lgkmcnt, leaves global loads/stores in flight
// (vmcnt waits land at use sites). __syncthreads would drain vmcnt(0).
__device__ __forceinline__ void bar() {
  __builtin_amdgcn_sched_barrier(0);
  asm volatile("s_waitcnt lgkmcnt(0)" ::: "memory");
  __builtin_amdgcn_s_barrier();
  __builtin_amdgcn_sched_barrier(0);
}

// ---------------------------------------------------------------------------
// Persistent bidirectional LSTM: 4-CHAIN ROTATING PIPELINE.
// grid = 128 blocks x 512 threads (latency-bound: 128 of 256 CUs busy).
// rk = blockIdx>>5 (slice 0..3, units [64rk,64rk+64) = 256 gate rows);
// q = blockIdx&31: dir = q>>4, batches b0..b0+3 (4 same-dir chains sharing
// the SAME weight registers). Thread: wv = tid>>6 (K-group, 48 k), lane
// row-quad (4 rows). wreg[4][12] float4 = 192 VGPRs.
//
// Iteration = 4 phases (A,B,C,D), each: [publish prev chain's flag (drained
// under prior section) | preload this phase's poll flag] -> GEMM (hides
// preload RT) -> bar -> section -> bar.  Section S_X: gate-wave(4+X): gates,
// h-store ISSUE only; fetch waves 0-3: stage chain X+1's h from in-flight
// regs, check preloaded flag (slow-path re-poll only on drift), issue next
// chain's h fetch; waves 0-1: emb stage+prefetch.  Every sync leg (drain,
// visibility, detect, fetch RT) has >= 1 phase (~1.2k cyc) of slack.
// Pipeline DAG is acyclic: every wait references a strictly earlier phase.
// ---------------------------------------------------------------------------
__global__ __launch_bounds__(512, 2) void lstm_kernel(
    const int* __restrict__ x, const float* __restrict__ embed,
    const float* __restrict__ Wih_f, const float* __restrict__ Whh_f,
    const float* __restrict__ bih_f, const float* __restrict__ bhh_f,
    const float* __restrict__ Wih_b, const float* __restrict__ Whh_b,
    const float* __restrict__ bih_b, const float* __restrict__ bhh_b,
    const float* __restrict__ h0, const float* __restrict__ c0,
    float* __restrict__ h_hist, u32* __restrict__ flags)
{
  const int rk   = blockIdx.x >> 5;   // slice 0..3
  const int q    = blockIdx.x & 31;
  const int dir  = q >> 4;
  const int b0   = (q & 15) * 4;
  const int bA = b0, bB = b0 + 1, bC = b0 + 2, bD = b0 + 3;
  const int chA = dir * BATCH + bA, chB = chA + 1, chC = chA + 2, chD = chA + 3;
  const int tid  = threadIdx.x;       // 0..511
  const int wv   = tid >> 6;          // wave 0..7 == K-group
  const int lane = tid & 63;          // row-quad index
  const int rb   = lane * 4;
  const int gi   = rb >> 6;
  const int grow0 = gi * 256 + rk * 64 + (rb & 63);

  const float* Wih = dir ? Wih_b : Wih_f;
  const float* Whh = dir ? Whh_b : Whh_f;
  const float* bih = dir ? bih_b : bih_f;
  const float* bhh = dir ? bhh_b : bhh_f;

  float4 wreg[4][12];
#pragma unroll
  for (int i = 0; i < 4; ++i)
#pragma unroll
    for (int c = 0; c < 12; ++c) {
      int k0 = wv * 48 + c * 4;
      if (k0 < 256)
        wreg[i][c] = *(const float4*)(Whh + (size_t)(grow0 + i) * 256 + k0);
      else
        wreg[i][c] = *(const float4*)(Wih + (size_t)(grow0 + i) * 128 + (k0 - 256));
    }
  const int kb = wv * 48;

  __shared__ float vA[384], vB[384], vC[384], vD[384];  // [h(256)|emb(128)]
  __shared__ float red[8 * 256];                        // shared across phases

  float bias4[4] = {0, 0, 0, 0};
  float creg = 0.0f;
  if (wv >= 4) {
    int b = b0 + (wv - 4);
#pragma unroll
    for (int gg = 0; gg < 4; ++gg)
      bias4[gg] = bih[gg * 256 + rk * 64 + lane] + bhh[gg * 256 + rk * 64 + lane];
    creg = c0[(size_t)(dir * BATCH + b) * HID + rk * 64 + lane];
  }

  auto TS = [&](int s) { s = s < SLEN ? s : SLEN - 1; return dir ? (SLEN - 1 - s) : s; };

  float evA = 0, evB = 0, evC = 0, evD = 0;
  int xvA = 0, xvB = 0, xvC = 0, xvD = 0;
  u32 hwA = 0, hwB = 0, hwC = 0, hwD = 0;

  // ---- prologue: h0 into all four v, emb_A(0) into vA; emb regs primed ----
  if (tid < 256) {
    vA[tid] = h0[(size_t)(dir * BATCH + bA) * HID + tid];
    vB[tid] = h0[(size_t)(dir * BATCH + bB) * HID + tid];
    vC[tid] = h0[(size_t)(dir * BATCH + bC) * HID + tid];
    vD[tid] = h0[(size_t)(dir * BATCH + bD) * HID + tid];
  }
  if (tid < 128) {
    vA[256 + tid] = embed[(size_t)x[bA * SLEN + TS(0)] * EMB + tid];
    evB = embed[(size_t)x[bB * SLEN + TS(0)] * EMB + tid]; xvB = x[bB * SLEN + TS(1)];
    evC = embed[(size_t)x[bC * SLEN + TS(0)] * EMB + tid]; xvC = x[bC * SLEN + TS(1)];
    evD = embed[(size_t)x[bD * SLEN + TS(0)] * EMB + tid]; xvD = x[bD * SLEN + TS(1)];
    evA = embed[(size_t)x[bA * SLEN + TS(1)] * EMB + tid]; xvA = x[bA * SLEN + TS(2)];
  }
  __syncthreads();

#define GEMM_PHASE(VV)                                                         \
  {                                                                            \
    float4 acc = {0, 0, 0, 0};                                                 \
    _Pragma("unroll")                                                          \
    for (int c = 0; c < 12; ++c) {                                             \
      float4 v4 = *(const float4*)&VV[kb + c * 4];                             \
      acc.x = fmaf(wreg[0][c].x, v4.x, acc.x); acc.x = fmaf(wreg[0][c].y, v4.y, acc.x); \
      acc.x = fmaf(wreg[0][c].z, v4.z, acc.x); acc.x = fmaf(wreg[0][c].w, v4.w, acc.x); \
      acc.y = fmaf(wreg[1][c].x, v4.x, acc.y); acc.y = fmaf(wreg[1][c].y, v4.y, acc.y); \
      acc.y = fmaf(wreg[1][c].z, v4.z, acc.y); acc.y = fmaf(wreg[1][c].w, v4.w, acc.y); \
      acc.z = fmaf(wreg[2][c].x, v4.x, acc.z); acc.z = fmaf(wreg[2][c].y, v4.y, acc.z); \
      acc.z = fmaf(wreg[2][c].z, v4.z, acc.z); acc.z = fmaf(wreg[2][c].w, v4.w, acc.z); \
      acc.w = fmaf(wreg[3][c].x, v4.x, acc.w); acc.w = fmaf(wreg[3][c].y, v4.y, acc.w); \
      acc.w = fmaf(wreg[3][c].z, v4.z, acc.w); acc.w = fmaf(wreg[3][c].w, v4.w, acc.w); \
    }                                                                          \
    *(float4*)&red[wv * 256 + rb] = acc;                                       \
  }

#define GATES(BX)                                                              \
  {                                                                            \
    float s0 = bias4[0], s1 = bias4[1], s2 = bias4[2], s3 = bias4[3];          \
    _Pragma("unroll")                                                          \
    for (int w = 0; w < 8; ++w) {                                              \
      s0 += red[w * 256 + lane];                                               \
      s1 += red[w * 256 + 64 + lane];                                          \
      s2 += red[w * 256 + 128 + lane];                                         \
      s3 += red[w * 256 + 192 + lane];                                         \
    }                                                                          \
    float ig = sigmoidf_(s0), fg = sigmoidf_(s1);                              \
    float gv = tanhf(s2), og = sigmoidf_(s3);                                  \
    creg = fg * creg + ig * gv;                                                \
    float hv = og * tanhf(creg);                                               \
    __hip_atomic_store(h_hist + ((size_t)(dir * SLEN + t) * BATCH + (BX)) * HID \
                         + rk * 64 + lane,                                     \
                       hv, __ATOMIC_RELAXED, __HIP_MEMORY_SCOPE_AGENT);        \
  }

#define PUBLISH(CH, ITX)                                                       \
  {                                                                            \
    asm volatile("s_waitcnt vmcnt(0)" ::: "memory");                           \
    if (lane == 0)                                                             \
      __hip_atomic_store(flags + ((size_t)(CH) * SLEN + (ITX)) * 4 + rk, 1u,   \
                         __ATOMIC_RELAXED, __HIP_MEMORY_SCOPE_AGENT);          \
  }

#define POLLCHK(PV, CH, ITX, BX, TPX, HW)                                      \
  {                                                                            \
    if (PV == 0) {                                                             \
      const u32* fp = flags + ((size_t)(CH) * SLEN + (ITX)) * 4 + wv;          \
      int sp = 0; u32 v = aload(fp);                                           \
      while (v == 0 && ++sp < (1 << 14)) { __builtin_amdgcn_s_sleep(1); v = aload(fp); } \
    }                                                                          \
    asm volatile("" ::: "memory");                                             \
    HW = aload((const u32*)(h_hist +                                           \
          ((size_t)(dir * SLEN + (TPX)) * BATCH + (BX)) * HID) + tid);         \
  }

#define EMBSTAGE(VV, EV, XV, BX, NEXTS)                                        \
  {                                                                            \
    VV[256 + tid] = EV;                                                        \
    EV = embed[(size_t)(XV) * EMB + tid];                                      \
    XV = x[(BX) * SLEN + TS(NEXTS)];                                           \
  }

  for (int it = 0; it < SLEN; ++it) {
    const int t  = dir ? (SLEN - 1 - it) : it;
    const int tp = dir ? (t + 1) : (t - 1);     // timestep of iteration it-1
    u32 pv;

    // ===== phase A =====
    if (wv == 7 && it > 0) PUBLISH(chD, it - 1)      // D's stores drained under S_D+
    pv = 1;
    if (wv < 4 && it > 0) pv = aload(flags + ((size_t)chC * SLEN + (it - 1)) * 4 + wv);
    __builtin_amdgcn_sched_barrier(0);
    GEMM_PHASE(vA)
    bar();
    if (wv == 4) { GATES(bA) }                       // issue only, drain next phase
    else if (wv < 4) {
      if (it > 0) { *(u32*)&vB[tid] = hwB; }         // vmcnt wait (flew 1 phase)
      if (it > 0) POLLCHK(pv, chC, it - 1, bC, tp, hwC)
      if (tid < 128) EMBSTAGE(vB, evB, xvB, bB, it + 2)
    }
    bar();

    // ===== phase B =====
    if (wv == 4) PUBLISH(chA, it)
    pv = 1;
    if (wv < 4 && it > 0) pv = aload(flags + ((size_t)chD * SLEN + (it - 1)) * 4 + wv);
    __builtin_amdgcn_sched_barrier(0);
    GEMM_PHASE(vB)
    bar();
    if (wv == 5) { GATES(bB) }
    else if (wv < 4) {
      if (it > 0) { *(u32*)&vC[tid] = hwC; }
      if (it > 0) POLLCHK(pv, chD, it - 1, bD, tp, hwD)
      if (tid < 128) EMBSTAGE(vC, evC, xvC, bC, it + 2)
    }
    bar();

    // ===== phase C =====
    if (wv == 5) PUBLISH(chB, it)
    pv = 1;
    if (wv < 4 && it < SLEN - 1) pv = aload(flags + ((size_t)chA * SLEN + it) * 4 + wv);
    __builtin_amdgcn_sched_barrier(0);
    GEMM_PHASE(vC)
    bar();
    if (wv == 6) { GATES(bC) }
    else if (wv < 4) {
      if (it > 0) { *(u32*)&vD[tid] = hwD; }
      if (it < SLEN - 1) POLLCHK(pv, chA, it, bA, t, hwA)
      if (tid < 128) EMBSTAGE(vD, evD, xvD, bD, it + 2)
    }
    bar();

    // ===== phase D =====
    if (wv == 6) PUBLISH(chC, it)
    pv = 1;
    if (wv < 4 && it < SLEN - 1) pv = aload(flags + ((size_t)chB * SLEN + it) * 4 + wv);
    __builtin_amdgcn_sched_barrier(0);
    GEMM_PHASE(vD)
    bar();
    if (wv == 7) { GATES(bD) }
    else if (wv < 4) {
      if (it < SLEN - 1) { *(u32*)&vA[tid] = hwA; }
      if (it < SLEN - 1) POLLCHK(pv, chB, it, bB, t, hwB)
      if (tid < 128) EMBSTAGE(vA, evA, xvA, bA, it + 3)   // emb_A(TS(it+1)) staged
    }
    bar();
  }
#undef GEMM_PHASE
#undef GATES
#undef PUBLISH
#undef POLLCHK
#undef EMBSTAGE
}

// ---------------------------------------------------------------------------
// feats[s][b][tag] = [hf|hb] . Wc[tag] + bc[tag]
// grid = (512/SB)*8 blocks (SB=16 timesteps, 8-batch chunk), 256 threads.
// ---------------------------------------------------------------------------
__global__ __launch_bounds__(256) void feats_kernel(
    const float* __restrict__ h_hist, const float* __restrict__ Wc,
    const float* __restrict__ bc, float* __restrict__ feats)
{
  const int s0  = (blockIdx.x >> 3) * SB;
  const int b0  = (blockIdx.x & 7) * FB;
  const int tid = threadIdx.x;
  __shared__ float wc[NT * 516];    // 37.2 KB
  __shared__ float hl[FB * 516];    // 16.5 KB
  __shared__ float bcl[NT];
  if (tid < NT) bcl[tid] = bc[tid];
  for (int f = tid * 4; f < NT * 512; f += 1024) {
    float4 v = *(const float4*)(Wc + f);
    *(float4*)&wc[(f >> 9) * 516 + (f & 511)] = v;
  }
  for (int si = 0; si < SB; ++si) {
    const int s = s0 + si;
    const float* src0 = h_hist + ((size_t)s * BATCH + b0) * HID;
    const float* src1 = h_hist + ((size_t)(SLEN + s) * BATCH + b0) * HID;
    for (int f = tid * 4; f < FB * 256; f += 1024) {
      int b = f >> 8, j = f & 255;
      *(float4*)&hl[b * 516 + j]       = *(const float4*)(src0 + f);
      *(float4*)&hl[b * 516 + 256 + j] = *(const float4*)(src1 + f);
    }
    __syncthreads();
    if (tid < FB * NT) {
      int b = tid / NT, tag = tid - b * NT;
      float a = bcl[tag];
      const float* hp = &hl[b * 516];
      const float* wp = &wc[tag * 516];
#pragma unroll 8
      for (int k = 0; k < 512; k += 4) {
        float4 h4 = *(const float4*)(hp + k);
        float4 w4 = *(const float4*)(wp + k);
        a = fmaf(h4.x, w4.x, a); a = fmaf(h4.y, w4.y, a);
        a = fmaf(h4.z, w4.z, a); a = fmaf(h4.w, w4.w, a);
      }
      feats[((size_t)s * BATCH + b0 + b) * NT + tag] = a;
    }
    __syncthreads();   // WAR guard before restaging hl
  }
}

// ---------------------------------------------------------------------------
// Viterbi + backtrace, one block per batch, 64 threads (1 wave).
// Whole per-batch feats panel bulk-staged into LDS; mask is monotone
// (arange < len by construction) so m_t == (t < len). Semantics identical
// to reference (exact add order, strict > first-max, masked bp=0, snapshot
// at t=len-1, decode[S-1]=pointer).
// ---------------------------------------------------------------------------
__global__ __launch_bounds__(64) void viterbi_kernel(
    const float* __restrict__ feats, const int* __restrict__ mask,
    const float* __restrict__ trans, float* __restrict__ out)
{
  const int b = blockIdx.x;
  const int lane = threadIdx.x;
  __shared__ float flds[SLEN * NT];        // 36.9 KB
  __shared__ float tr[NT][NT + 1];
  __shared__ float part[2][NT + 2];
  __shared__ float lastp[NT + 2];
  __shared__ unsigned char bp[SLEN][20];   // 10.2 KB
  __shared__ int len_s;

  for (int f = lane; f < SLEN * NT; f += 64) {
    int s = f / NT, tag = f - s * NT;
    flds[f] = feats[((size_t)s * BATCH + b) * NT + tag];
  }
  for (int f = lane; f < NT * NT; f += 64) tr[f / NT][f % NT] = trans[f];
  int m = 0;
#pragma unroll
  for (int i = 0; i < 8; ++i) m += mask[b * SLEN + lane * 8 + i];
  for (int off = 32; off; off >>= 1) m += __shfl_down(m, off);
  if (lane == 0) len_s = m;
  __syncthreads();
  const int len = len_s;

  if (lane < NT) part[0][lane] = flds[lane] + tr[16][lane];   // START=16
  __syncthreads();

  int cur = 0;
  for (int t = 1; t < SLEN; ++t) {
    if (lane < NT) {
      float fcur = flds[t * NT + lane];
      float best = -3.0e38f; int bf = 0;
#pragma unroll
      for (int from = 0; from < NT; ++from) {
        float v = (fcur + tr[from][lane]) + part[cur][from];  // exact ref order
        if (v > best) { best = v; bf = from; }
      }
      part[cur ^ 1][lane] = best;
      bp[t][lane] = (t < len) ? (unsigned char)bf : (unsigned char)0;
      if (t == len - 1) lastp[lane] = best;
    }
    cur ^= 1;
    __syncthreads();
  }

  if (lane == 0) {
    float best = -3.0e38f; int bf = 0;
    for (int from = 0; from < NT; ++from) {
      float v = lastp[from] + tr[from][17];      // END=17
      if (v > best) { best = v; bf = from; }
    }
    out[b] = best;                                // path_score
    int ptr = bf;
    out[BATCH + (size_t)b * SLEN + (SLEN - 1)] = (float)ptr;
    for (int i = SLEN - 2; i >= 0; --i) {
      int nw = (i == len - 1) ? bf : (int)bp[i + 1][ptr];
      out[BATCH + (size_t)b * SLEN + i] = (float)nw;
      ptr = nw;
    }
  }
}

// ---------------------------------------------------------------------------
extern "C" void kernel_launch(void* const* d_in, const int* in_sizes, int n_in,
                              void* d_out, int out_size, void* d_ws, size_t ws_size,
                              hipStream_t stream) {
  const int*   x      = (const int*)  d_in[0];
  const int*   mask   = (const int*)  d_in[1];
  const float* embed  = (const float*)d_in[2];
  const float* Wih_f  = (const float*)d_in[3];
  const float* Whh_f  = (const float*)d_in[4];
  const float* bih_f  = (const float*)d_in[5];
  const float* bhh_f  = (const float*)d_in[6];
  const float* Wih_b  = (const float*)d_in[7];
  const float* Whh_b  = (const float*)d_in[8];
  const float* bih_b  = (const float*)d_in[9];
  const float* bhh_b  = (const float*)d_in[10];
  const float* Wc     = (const float*)d_in[11];
  const float* bc     = (const float*)d_in[12];
  const float* trans  = (const float*)d_in[13];
  const float* h0     = (const float*)d_in[14];
  const float* c0     = (const float*)d_in[15];
  float* out = (float*)d_out;

  // ws layout: h_hist @0 (64MB); flags and feats SHARE ws+64MB (disjoint in
  // time; flags re-zeroed each launch -> graph-replay deterministic).
  char* ws = (char*)d_ws;
  float* h_hist = (float*)ws;                                 // 64 MB
  u32*   flags  = (u32*)(ws + (size_t)67108864);              // 1 MB
  float* feats  = (float*)(ws + (size_t)67108864);            // 2.25 MB (aliases flags)

  hipMemsetAsync(flags, 0, (size_t)NCHAIN * SLEN * 4 * sizeof(u32), stream);
  lstm_kernel<<<128, 512, 0, stream>>>(x, embed, Wih_f, Whh_f, bih_f, bhh_f,
                                       Wih_b, Whh_b, bih_b, bhh_b, h0, c0,
                                       h_hist, flags);
  feats_kernel<<<(SLEN / SB) * 8, 256, 0, stream>>>(h_hist, Wc, bc, feats);
  viterbi_kernel<<<BATCH, 64, 0, stream>>>(feats, mask, trans, out);
}

// Round 16
// 2017.243 us; speedup vs baseline: 1.6986x; 1.6986x over previous
//
#include <hip/hip_runtime.h>

#define SLEN 512
#define BATCH 64
#define HID 256
#define EMB 128
#define NT 18
#define NCHAIN 128        // 2 dirs x 64 batches
#define FB 8              // batches per feats block
#define SB 16             // timesteps per feats block

typedef unsigned int u32;

__device__ __forceinline__ float sigmoidf_(float v) { return 1.0f / (1.0f + expf(-v)); }
__device__ __forceinline__ u32 aload(const u32* p) {
  return __hip_atomic_load((u32*)p, __ATOMIC_RELAXED, __HIP_MEMORY_SCOPE_AGENT);
}
// LDS-only barrier: drains lgkmcnt, leaves global loads in flight (vmcnt
// waits land at use sites). __syncthreads would drain vmcnt(0).
__device__ __forceinline__ void bar() {
  __builtin_amdgcn_sched_barrier(0);
  asm volatile("s_waitcnt lgkmcnt(0)" ::: "memory");
  __builtin_amdgcn_s_barrier();
  __builtin_amdgcn_sched_barrier(0);
}

// ---------------------------------------------------------------------------
// Persistent bidirectional LSTM (R13 structure, frozen: best = 1750 us).
// Two-chain interleave, 4-row GEMM tiling, raw lgkm-only barriers,
// split-issue fetch for chain B, per-slice flag words, 4-slice rendezvous,
// 2 blocks/CU co-residency. Verified best across R4..R15 exploration:
// counter-RMW (R8), hot-spin (R10), data-poll (R6), 4-chain rotation (R15)
// all regressed; exchange is bound by IC round-trip latency.
// ---------------------------------------------------------------------------
__global__ __launch_bounds__(512, 2) void lstm_kernel(
    const int* __restrict__ x, const float* __restrict__ embed,
    const float* __restrict__ Wih_f, const float* __restrict__ Whh_f,
    const float* __restrict__ bih_f, const float* __restrict__ bhh_f,
    const float* __restrict__ Wih_b, const float* __restrict__ Whh_b,
    const float* __restrict__ bih_b, const float* __restrict__ bhh_b,
    const float* __restrict__ h0, const float* __restrict__ c0,
    float* __restrict__ h_hist, u32* __restrict__ flags)
{
  const int rk   = blockIdx.x >> 6;   // slice 0..3
  const int q    = blockIdx.x & 63;
  const int dir  = q >> 5;
  const int bA   = (q & 31) * 2, bB = bA + 1;
  const int chA  = dir * BATCH + bA, chB = chA + 1;
  const int tid  = threadIdx.x;       // 0..511
  const int wv   = tid >> 6;          // wave 0..7 == K-group
  const int lane = tid & 63;          // row-quad index
  const int rb   = lane * 4;          // row base (4 rows, same gate)
  const int gi   = rb >> 6;
  const int grow0 = gi * 256 + rk * 64 + (rb & 63);   // 4 consecutive W rows

  const float* Wih = dir ? Wih_b : Wih_f;
  const float* Whh = dir ? Whh_b : Whh_f;
  const float* bih = dir ? bih_b : bih_f;
  const float* bhh = dir ? bhh_b : bhh_f;

  float4 wreg[4][12];
#pragma unroll
  for (int i = 0; i < 4; ++i)
#pragma unroll
    for (int c = 0; c < 12; ++c) {
      int k0 = wv * 48 + c * 4;
      if (k0 < 256)
        wreg[i][c] = *(const float4*)(Whh + (size_t)(grow0 + i) * 256 + k0);
      else
        wreg[i][c] = *(const float4*)(Wih + (size_t)(grow0 + i) * 128 + (k0 - 256));
    }

  __shared__ float vA[384], vB[384];              // [h(256) | emb(128)]
  __shared__ float redA[8 * 256], redB[8 * 256];  // [kg][row]

  float bias4[4] = {0, 0, 0, 0};
  float creg = 0.0f;
  if (wv >= 6) {
    int b = (wv == 6) ? bA : bB;
#pragma unroll
    for (int gg = 0; gg < 4; ++gg)
      bias4[gg] = bih[gg * 256 + rk * 64 + lane] + bhh[gg * 256 + rk * 64 + lane];
    creg = c0[(size_t)(dir * BATCH + b) * HID + rk * 64 + lane];
  }

  auto TS = [&](int s) { s = s < SLEN ? s : SLEN - 1; return dir ? (SLEN - 1 - s) : s; };

  const int ee = tid - 256;           // emb element for w4,5
  float evA = 0.0f, evB = 0.0f;
  int xvA = 0, xvB = 0;
  u32 hwB = 0;

  if (tid < 256) {
    vA[tid] = h0[(size_t)(dir * BATCH + bA) * HID + tid];
    vB[tid] = h0[(size_t)(dir * BATCH + bB) * HID + tid];
  } else if (tid < 384) {
    vA[256 + ee] = embed[(size_t)x[bA * SLEN + TS(0)] * EMB + ee];
    evA = embed[(size_t)x[bA * SLEN + TS(1)] * EMB + ee];
    xvA = x[bA * SLEN + TS(2)];
    evB = embed[(size_t)x[bB * SLEN + TS(0)] * EMB + ee];
    xvB = x[bB * SLEN + TS(1)];
  }
  __syncthreads();

  for (int it = 0; it < SLEN; ++it) {
    const int t = dir ? (SLEN - 1 - it) : it;
    const int kb = wv * 48;

    // ================= GEMM A =================
    {
      float4 acc = {0, 0, 0, 0};
#pragma unroll
      for (int c = 0; c < 12; ++c) {
        float4 v4 = *(const float4*)&vA[kb + c * 4];   // broadcast read
        acc.x = fmaf(wreg[0][c].x, v4.x, acc.x); acc.x = fmaf(wreg[0][c].y, v4.y, acc.x);
        acc.x = fmaf(wreg[0][c].z, v4.z, acc.x); acc.x = fmaf(wreg[0][c].w, v4.w, acc.x);
        acc.y = fmaf(wreg[1][c].x, v4.x, acc.y); acc.y = fmaf(wreg[1][c].y, v4.y, acc.y);
        acc.y = fmaf(wreg[1][c].z, v4.z, acc.y); acc.y = fmaf(wreg[1][c].w, v4.w, acc.y);
        acc.z = fmaf(wreg[2][c].x, v4.x, acc.z); acc.z = fmaf(wreg[2][c].y, v4.y, acc.z);
        acc.z = fmaf(wreg[2][c].z, v4.z, acc.z); acc.z = fmaf(wreg[2][c].w, v4.w, acc.z);
        acc.w = fmaf(wreg[3][c].x, v4.x, acc.w); acc.w = fmaf(wreg[3][c].y, v4.y, acc.w);
        acc.w = fmaf(wreg[3][c].z, v4.z, acc.w); acc.w = fmaf(wreg[3][c].w, v4.w, acc.w);
      }
      *(float4*)&redA[wv * 256 + rb] = acc;
    }
    bar();                                             // S1

    // ---- sec1: gates A | stage vB h (in-flight hwB) | vB emb -------------
    if (wv == 6) {
      float s0 = bias4[0], s1 = bias4[1], s2 = bias4[2], s3 = bias4[3];
#pragma unroll
      for (int w = 0; w < 8; ++w) {
        s0 += redA[w * 256 + lane];
        s1 += redA[w * 256 + 64 + lane];
        s2 += redA[w * 256 + 128 + lane];
        s3 += redA[w * 256 + 192 + lane];
      }
      float ig = sigmoidf_(s0), fg = sigmoidf_(s1);
      float gv = tanhf(s2),     og = sigmoidf_(s3);
      creg = fg * creg + ig * gv;
      float hv = og * tanhf(creg);
      __hip_atomic_store(h_hist + ((size_t)(dir * SLEN + t) * BATCH + bA) * HID
                           + rk * 64 + lane,
                         hv, __ATOMIC_RELAXED, __HIP_MEMORY_SCOPE_AGENT);
      asm volatile("s_waitcnt vmcnt(0)" ::: "memory");
      if (lane == 0)
        __hip_atomic_store(flags + ((size_t)chA * SLEN + it) * 4 + rk, 1u,
                           __ATOMIC_RELAXED, __HIP_MEMORY_SCOPE_AGENT);
    } else if (tid < 256) {
      if (it > 0) *(u32*)&vB[tid] = hwB;   // vmcnt wait here (drained under GEMM A)
    } else if (wv < 6) {
      vB[256 + ee] = evB;
      evB = embed[(size_t)xvB * EMB + ee];
      xvB = x[bB * SLEN + TS(it + 2)];
    }
    bar();                                             // S2

    // ================= GEMM B =================
    {
      float4 acc = {0, 0, 0, 0};
#pragma unroll
      for (int c = 0; c < 12; ++c) {
        float4 v4 = *(const float4*)&vB[kb + c * 4];   // broadcast read
        acc.x = fmaf(wreg[0][c].x, v4.x, acc.x); acc.x = fmaf(wreg[0][c].y, v4.y, acc.x);
        acc.x = fmaf(wreg[0][c].z, v4.z, acc.x); acc.x = fmaf(wreg[0][c].w, v4.w, acc.x);
        acc.y = fmaf(wreg[1][c].x, v4.x, acc.y); acc.y = fmaf(wreg[1][c].y, v4.y, acc.y);
        acc.y = fmaf(wreg[1][c].z, v4.z, acc.y); acc.y = fmaf(wreg[1][c].w, v4.w, acc.y);
        acc.z = fmaf(wreg[2][c].x, v4.x, acc.z); acc.z = fmaf(wreg[2][c].y, v4.y, acc.z);
        acc.z = fmaf(wreg[2][c].z, v4.z, acc.z); acc.z = fmaf(wreg[2][c].w, v4.w, acc.z);
        acc.w = fmaf(wreg[3][c].x, v4.x, acc.w); acc.w = fmaf(wreg[3][c].y, v4.y, acc.w);
        acc.w = fmaf(wreg[3][c].z, v4.z, acc.w); acc.w = fmaf(wreg[3][c].w, v4.w, acc.w);
      }
      *(float4*)&redB[wv * 256 + rb] = acc;
    }
    bar();                                             // S3

    // ---- sec2: gates B | fetch+stage vA, poll+issue hwB | vA emb ---------
    if (wv == 7) {
      float s0 = bias4[0], s1 = bias4[1], s2 = bias4[2], s3 = bias4[3];
#pragma unroll
      for (int w = 0; w < 8; ++w) {
        s0 += redB[w * 256 + lane];
        s1 += redB[w * 256 + 64 + lane];
        s2 += redB[w * 256 + 128 + lane];
        s3 += redB[w * 256 + 192 + lane];
      }
      float ig = sigmoidf_(s0), fg = sigmoidf_(s1);
      float gv = tanhf(s2),     og = sigmoidf_(s3);
      creg = fg * creg + ig * gv;
      float hv = og * tanhf(creg);
      __hip_atomic_store(h_hist + ((size_t)(dir * SLEN + t) * BATCH + bB) * HID
                           + rk * 64 + lane,
                         hv, __ATOMIC_RELAXED, __HIP_MEMORY_SCOPE_AGENT);
      asm volatile("s_waitcnt vmcnt(0)" ::: "memory");
      if (lane == 0)
        __hip_atomic_store(flags + ((size_t)chB * SLEN + it) * 4 + rk, 1u,
                           __ATOMIC_RELAXED, __HIP_MEMORY_SCOPE_AGENT);
    } else if (tid < 256) {
      if (it < SLEN - 1) {
        const u32* fpA = flags + ((size_t)chA * SLEN + it) * 4 + wv;
        u32 v = aload(fpA); int sp = 0;
        while (v == 0 && ++sp < (1 << 14)) { __builtin_amdgcn_s_sleep(1); v = aload(fpA); }
        asm volatile("" ::: "memory");
        u32 ha = aload((const u32*)(h_hist +
                   ((size_t)(dir * SLEN + t) * BATCH + bA) * HID) + tid);
        *(u32*)&vA[tid] = ha;
        const u32* fpB = flags + ((size_t)chB * SLEN + it) * 4 + wv;
        v = aload(fpB); sp = 0;
        while (v == 0 && ++sp < (1 << 14)) { __builtin_amdgcn_s_sleep(1); v = aload(fpB); }
        asm volatile("" ::: "memory");
        hwB = aload((const u32*)(h_hist +
                 ((size_t)(dir * SLEN + t) * BATCH + bB) * HID) + tid);
      }
    } else if (wv < 6) {
      if (it < SLEN - 1) {
        vA[256 + ee] = evA;
        evA = embed[(size_t)xvA * EMB + ee];
        xvA = x[bA * SLEN + TS(it + 3)];
      }
    }
    bar();                                             // S4
  }
}

// ---------------------------------------------------------------------------
// feats[s][b][tag] = [hf|hb] . Wc[tag] + bc[tag]
// grid = (512/SB)*8 blocks (SB=16 timesteps, 8-batch chunk), 256 threads.
// Wc staged ONCE per block, reused for 16 timesteps.
// ---------------------------------------------------------------------------
__global__ __launch_bounds__(256) void feats_kernel(
    const float* __restrict__ h_hist, const float* __restrict__ Wc,
    const float* __restrict__ bc, float* __restrict__ feats)
{
  const int s0  = (blockIdx.x >> 3) * SB;
  const int b0  = (blockIdx.x & 7) * FB;
  const int tid = threadIdx.x;
  __shared__ float wc[NT * 516];    // 37.2 KB
  __shared__ float hl[FB * 516];    // 16.5 KB
  __shared__ float bcl[NT];
  if (tid < NT) bcl[tid] = bc[tid];
  for (int f = tid * 4; f < NT * 512; f += 1024) {
    float4 v = *(const float4*)(Wc + f);
    *(float4*)&wc[(f >> 9) * 516 + (f & 511)] = v;
  }
  for (int si = 0; si < SB; ++si) {
    const int s = s0 + si;
    const float* src0 = h_hist + ((size_t)s * BATCH + b0) * HID;
    const float* src1 = h_hist + ((size_t)(SLEN + s) * BATCH + b0) * HID;
    for (int f = tid * 4; f < FB * 256; f += 1024) {
      int b = f >> 8, j = f & 255;
      *(float4*)&hl[b * 516 + j]       = *(const float4*)(src0 + f);
      *(float4*)&hl[b * 516 + 256 + j] = *(const float4*)(src1 + f);
    }
    __syncthreads();
    if (tid < FB * NT) {
      int b = tid / NT, tag = tid - b * NT;
      float a = bcl[tag];
      const float* hp = &hl[b * 516];
      const float* wp = &wc[tag * 516];
#pragma unroll 8
      for (int k = 0; k < 512; k += 4) {
        float4 h4 = *(const float4*)(hp + k);
        float4 w4 = *(const float4*)(wp + k);
        a = fmaf(h4.x, w4.x, a); a = fmaf(h4.y, w4.y, a);
        a = fmaf(h4.z, w4.z, a); a = fmaf(h4.w, w4.w, a);
      }
      feats[((size_t)s * BATCH + b0 + b) * NT + tag] = a;
    }
    __syncthreads();   // WAR guard before restaging hl
  }
}

// ---------------------------------------------------------------------------
// Viterbi + backtrace, one block per batch, 64 threads (1 wave).
// Whole per-batch feats panel (512x18 = 36.9 KB) bulk-staged into LDS up
// front (coalesced, IC-hot) -> main loop pure LDS/VALU. mask is monotone
// (arange < len by construction) so m_t == (t < len). Semantics identical
// to reference (exact add order, strict > first-max, masked bp=0, snapshot
// at t=len-1, decode[S-1]=pointer).
// ---------------------------------------------------------------------------
__global__ __launch_bounds__(64) void viterbi_kernel(
    const float* __restrict__ feats, const int* __restrict__ mask,
    const float* __restrict__ trans, float* __restrict__ out)
{
  const int b = blockIdx.x;
  const int lane = threadIdx.x;
  __shared__ float flds[SLEN * NT];        // 36.9 KB
  __shared__ float tr[NT][NT + 1];
  __shared__ float part[2][NT + 2];
  __shared__ float lastp[NT + 2];
  __shared__ unsigned char bp[SLEN][20];   // 10.2 KB
  __shared__ int len_s;

  for (int f = lane; f < SLEN * NT; f += 64) {
    int s = f / NT, tag = f - s * NT;
    flds[f] = feats[((size_t)s * BATCH + b) * NT + tag];
  }
  for (int f = lane; f < NT * NT; f += 64) tr[f / NT][f % NT] = trans[f];
  int m = 0;
#pragma unroll
  for (int i = 0; i < 8; ++i) m += mask[b * SLEN + lane * 8 + i];
  for (int off = 32; off; off >>= 1) m += __shfl_down(m, off);
  if (lane == 0) len_s = m;
  __syncthreads();
  const int len = len_s;

  if (lane < NT) part[0][lane] = flds[lane] + tr[16][lane];   // START=16
  __syncthreads();

  int cur = 0;
  for (int t = 1; t < SLEN; ++t) {
    if (lane < NT) {
      float fcur = flds[t * NT + lane];
      float best = -3.0e38f; int bf = 0;
#pragma unroll
      for (int from = 0; from < NT; ++from) {
        float v = (fcur + tr[from][lane]) + part[cur][from];  // exact ref order
        if (v > best) { best = v; bf = from; }
      }
      part[cur ^ 1][lane] = best;
      bp[t][lane] = (t < len) ? (unsigned char)bf : (unsigned char)0;
      if (t == len - 1) lastp[lane] = best;
    }
    cur ^= 1;
    __syncthreads();
  }

  if (lane == 0) {
    float best = -3.0e38f; int bf = 0;
    for (int from = 0; from < NT; ++from) {
      float v = lastp[from] + tr[from][17];      // END=17
      if (v > best) { best = v; bf = from; }
    }
    out[b] = best;                                // path_score
    int ptr = bf;
    out[BATCH + (size_t)b * SLEN + (SLEN - 1)] = (float)ptr;
    for (int i = SLEN - 2; i >= 0; --i) {
      int nw = (i == len - 1) ? bf : (int)bp[i + 1][ptr];
      out[BATCH + (size_t)b * SLEN + i] = (float)nw;
      ptr = nw;
    }
  }
}

// ---------------------------------------------------------------------------
extern "C" void kernel_launch(void* const* d_in, const int* in_sizes, int n_in,
                              void* d_out, int out_size, void* d_ws, size_t ws_size,
                              hipStream_t stream) {
  const int*   x      = (const int*)  d_in[0];
  const int*   mask   = (const int*)  d_in[1];
  const float* embed  = (const float*)d_in[2];
  const float* Wih_f  = (const float*)d_in[3];
  const float* Whh_f  = (const float*)d_in[4];
  const float* bih_f  = (const float*)d_in[5];
  const float* bhh_f  = (const float*)d_in[6];
  const float* Wih_b  = (const float*)d_in[7];
  const float* Whh_b  = (const float*)d_in[8];
  const float* bih_b  = (const float*)d_in[9];
  const float* bhh_b  = (const float*)d_in[10];
  const float* Wc     = (const float*)d_in[11];
  const float* bc     = (const float*)d_in[12];
  const float* trans  = (const float*)d_in[13];
  const float* h0     = (const float*)d_in[14];
  const float* c0     = (const float*)d_in[15];
  float* out = (float*)d_out;

  // ws layout: h_hist @0 (64MB); flags and feats SHARE ws+64MB (disjoint in
  // time; flags re-zeroed each launch -> graph-replay deterministic).
  char* ws = (char*)d_ws;
  float* h_hist = (float*)ws;                                 // 64 MB
  u32*   flags  = (u32*)(ws + (size_t)67108864);              // 1 MB
  float* feats  = (float*)(ws + (size_t)67108864);            // 2.25 MB (aliases flags)

  hipMemsetAsync(flags, 0, (size_t)NCHAIN * SLEN * 4 * sizeof(u32), stream);
  lstm_kernel<<<256, 512, 0, stream>>>(x, embed, Wih_f, Whh_f, bih_f, bhh_f,
                                       Wih_b, Whh_b, bih_b, bhh_b, h0, c0,
                                       h_hist, flags);
  feats_kernel<<<(SLEN / SB) * 8, 256, 0, stream>>>(h_hist, Wc, bc, feats);
  viterbi_kernel<<<BATCH, 64, 0, stream>>>(feats, mask, trans, out);
}

// Round 17
// 2016.047 us; speedup vs baseline: 1.6996x; 1.0006x over previous
//
#include <hip/hip_runtime.h>

#define SLEN 512
#define BATCH 64
#define HID 256
#define EMB 128
#define NT 18
#define NCHAIN 128        // 2 dirs x 64 batches
#define FB 8              // batches per feats block
#define SB 16             // timesteps per feats block

typedef unsigned int u32;

__device__ __forceinline__ float sigmoidf_(float v) { return 1.0f / (1.0f + expf(-v)); }
__device__ __forceinline__ u32 aload(const u32* p) {
  return __hip_atomic_load((u32*)p, __ATOMIC_RELAXED, __HIP_MEMORY_SCOPE_AGENT);
}
// LDS-only barrier: drains lgkmcnt, leaves global loads in flight (vmcnt
// waits land at use sites). __syncthreads would drain vmcnt(0).
__device__ __forceinline__ void bar() {
  __builtin_amdgcn_sched_barrier(0);
  asm volatile("s_waitcnt lgkmcnt(0)" ::: "memory");
  __builtin_amdgcn_s_barrier();
  __builtin_amdgcn_sched_barrier(0);
}

// ---------------------------------------------------------------------------
// Persistent bidirectional LSTM (R13 structure + sec2 latency-overlap).
// Two-chain interleave, 4-row GEMM tiling, raw lgkm-only barriers,
// split-issue fetch for chain B, per-slice flag words, 4-slice rendezvous,
// 2 blocks/CU co-residency.
// R17 deltas vs R16 (protocol unchanged, order only):
//  - flagA(it) preloaded during GEMM B (issue pinned by sched_barrier;
//    RT hides under 192 FMA; common case skips sec2's detect-A leg).
//  - sec2: issue hA -> poll B (spin covers hA's fetch RT) -> issue hwB ->
//    stage vA (hA long landed). Removes the exposed hA RT.
// ---------------------------------------------------------------------------
__global__ __launch_bounds__(512, 2) void lstm_kernel(
    const int* __restrict__ x, const float* __restrict__ embed,
    const float* __restrict__ Wih_f, const float* __restrict__ Whh_f,
    const float* __restrict__ bih_f, const float* __restrict__ bhh_f,
    const float* __restrict__ Wih_b, const float* __restrict__ Whh_b,
    const float* __restrict__ bih_b, const float* __restrict__ bhh_b,
    const float* __restrict__ h0, const float* __restrict__ c0,
    float* __restrict__ h_hist, u32* __restrict__ flags)
{
  const int rk   = blockIdx.x >> 6;   // slice 0..3
  const int q    = blockIdx.x & 63;
  const int dir  = q >> 5;
  const int bA   = (q & 31) * 2, bB = bA + 1;
  const int chA  = dir * BATCH + bA, chB = chA + 1;
  const int tid  = threadIdx.x;       // 0..511
  const int wv   = tid >> 6;          // wave 0..7 == K-group
  const int lane = tid & 63;          // row-quad index
  const int rb   = lane * 4;          // row base (4 rows, same gate)
  const int gi   = rb >> 6;
  const int grow0 = gi * 256 + rk * 64 + (rb & 63);   // 4 consecutive W rows

  const float* Wih = dir ? Wih_b : Wih_f;
  const float* Whh = dir ? Whh_b : Whh_f;
  const float* bih = dir ? bih_b : bih_f;
  const float* bhh = dir ? bhh_b : bhh_f;

  float4 wreg[4][12];
#pragma unroll
  for (int i = 0; i < 4; ++i)
#pragma unroll
    for (int c = 0; c < 12; ++c) {
      int k0 = wv * 48 + c * 4;
      if (k0 < 256)
        wreg[i][c] = *(const float4*)(Whh + (size_t)(grow0 + i) * 256 + k0);
      else
        wreg[i][c] = *(const float4*)(Wih + (size_t)(grow0 + i) * 128 + (k0 - 256));
    }

  __shared__ float vA[384], vB[384];              // [h(256) | emb(128)]
  __shared__ float redA[8 * 256], redB[8 * 256];  // [kg][row]

  float bias4[4] = {0, 0, 0, 0};
  float creg = 0.0f;
  if (wv >= 6) {
    int b = (wv == 6) ? bA : bB;
#pragma unroll
    for (int gg = 0; gg < 4; ++gg)
      bias4[gg] = bih[gg * 256 + rk * 64 + lane] + bhh[gg * 256 + rk * 64 + lane];
    creg = c0[(size_t)(dir * BATCH + b) * HID + rk * 64 + lane];
  }

  auto TS = [&](int s) { s = s < SLEN ? s : SLEN - 1; return dir ? (SLEN - 1 - s) : s; };

  const int ee = tid - 256;           // emb element for w4,5
  float evA = 0.0f, evB = 0.0f;
  int xvA = 0, xvB = 0;
  u32 hwB = 0;

  if (tid < 256) {
    vA[tid] = h0[(size_t)(dir * BATCH + bA) * HID + tid];
    vB[tid] = h0[(size_t)(dir * BATCH + bB) * HID + tid];
  } else if (tid < 384) {
    vA[256 + ee] = embed[(size_t)x[bA * SLEN + TS(0)] * EMB + ee];
    evA = embed[(size_t)x[bA * SLEN + TS(1)] * EMB + ee];
    xvA = x[bA * SLEN + TS(2)];
    evB = embed[(size_t)x[bB * SLEN + TS(0)] * EMB + ee];
    xvB = x[bB * SLEN + TS(1)];
  }
  __syncthreads();

  for (int it = 0; it < SLEN; ++it) {
    const int t = dir ? (SLEN - 1 - it) : it;
    const int kb = wv * 48;

    // ================= GEMM A =================
    {
      float4 acc = {0, 0, 0, 0};
#pragma unroll
      for (int c = 0; c < 12; ++c) {
        float4 v4 = *(const float4*)&vA[kb + c * 4];   // broadcast read
        acc.x = fmaf(wreg[0][c].x, v4.x, acc.x); acc.x = fmaf(wreg[0][c].y, v4.y, acc.x);
        acc.x = fmaf(wreg[0][c].z, v4.z, acc.x); acc.x = fmaf(wreg[0][c].w, v4.w, acc.x);
        acc.y = fmaf(wreg[1][c].x, v4.x, acc.y); acc.y = fmaf(wreg[1][c].y, v4.y, acc.y);
        acc.y = fmaf(wreg[1][c].z, v4.z, acc.y); acc.y = fmaf(wreg[1][c].w, v4.w, acc.y);
        acc.z = fmaf(wreg[2][c].x, v4.x, acc.z); acc.z = fmaf(wreg[2][c].y, v4.y, acc.z);
        acc.z = fmaf(wreg[2][c].z, v4.z, acc.z); acc.z = fmaf(wreg[2][c].w, v4.w, acc.z);
        acc.w = fmaf(wreg[3][c].x, v4.x, acc.w); acc.w = fmaf(wreg[3][c].y, v4.y, acc.w);
        acc.w = fmaf(wreg[3][c].z, v4.z, acc.w); acc.w = fmaf(wreg[3][c].w, v4.w, acc.w);
      }
      *(float4*)&redA[wv * 256 + rb] = acc;
    }
    bar();                                             // S1

    // ---- sec1: gates A | stage vB h (in-flight hwB) | vB emb -------------
    if (wv == 6) {
      float s0 = bias4[0], s1 = bias4[1], s2 = bias4[2], s3 = bias4[3];
#pragma unroll
      for (int w = 0; w < 8; ++w) {
        s0 += redA[w * 256 + lane];
        s1 += redA[w * 256 + 64 + lane];
        s2 += redA[w * 256 + 128 + lane];
        s3 += redA[w * 256 + 192 + lane];
      }
      float ig = sigmoidf_(s0), fg = sigmoidf_(s1);
      float gv = tanhf(s2),     og = sigmoidf_(s3);
      creg = fg * creg + ig * gv;
      float hv = og * tanhf(creg);
      __hip_atomic_store(h_hist + ((size_t)(dir * SLEN + t) * BATCH + bA) * HID
                           + rk * 64 + lane,
                         hv, __ATOMIC_RELAXED, __HIP_MEMORY_SCOPE_AGENT);
      asm volatile("s_waitcnt vmcnt(0)" ::: "memory");
      if (lane == 0)
        __hip_atomic_store(flags + ((size_t)chA * SLEN + it) * 4 + rk, 1u,
                           __ATOMIC_RELAXED, __HIP_MEMORY_SCOPE_AGENT);
    } else if (tid < 256) {
      if (it > 0) *(u32*)&vB[tid] = hwB;   // vmcnt wait here (drained under GEMM A)
    } else if (wv < 6) {
      vB[256 + ee] = evB;
      evB = embed[(size_t)xvB * EMB + ee];
      xvB = x[bB * SLEN + TS(it + 2)];
    }
    bar();                                             // S2

    // ---- preload flagA(it) check; RT hides under GEMM B ------------------
    u32 pvA = 1;
    if (wv < 4 && it < SLEN - 1)
      pvA = aload(flags + ((size_t)chA * SLEN + it) * 4 + wv);
    __builtin_amdgcn_sched_barrier(0);   // pin issue before GEMM B

    // ================= GEMM B =================
    {
      float4 acc = {0, 0, 0, 0};
#pragma unroll
      for (int c = 0; c < 12; ++c) {
        float4 v4 = *(const float4*)&vB[kb + c * 4];   // broadcast read
        acc.x = fmaf(wreg[0][c].x, v4.x, acc.x); acc.x = fmaf(wreg[0][c].y, v4.y, acc.x);
        acc.x = fmaf(wreg[0][c].z, v4.z, acc.x); acc.x = fmaf(wreg[0][c].w, v4.w, acc.x);
        acc.y = fmaf(wreg[1][c].x, v4.x, acc.y); acc.y = fmaf(wreg[1][c].y, v4.y, acc.y);
        acc.y = fmaf(wreg[1][c].z, v4.z, acc.y); acc.y = fmaf(wreg[1][c].w, v4.w, acc.y);
        acc.z = fmaf(wreg[2][c].x, v4.x, acc.z); acc.z = fmaf(wreg[2][c].y, v4.y, acc.z);
        acc.z = fmaf(wreg[2][c].z, v4.z, acc.z); acc.z = fmaf(wreg[2][c].w, v4.w, acc.z);
        acc.w = fmaf(wreg[3][c].x, v4.x, acc.w); acc.w = fmaf(wreg[3][c].y, v4.y, acc.w);
        acc.w = fmaf(wreg[3][c].z, v4.z, acc.w); acc.w = fmaf(wreg[3][c].w, v4.w, acc.w);
      }
      *(float4*)&redB[wv * 256 + rb] = acc;
    }
    bar();                                             // S3

    // ---- sec2: gates B | [chk A, issue hA, poll B (covers hA RT),
    //                        issue hwB, stage vA] | vA emb -----------------
    if (wv == 7) {
      float s0 = bias4[0], s1 = bias4[1], s2 = bias4[2], s3 = bias4[3];
#pragma unroll
      for (int w = 0; w < 8; ++w) {
        s0 += redB[w * 256 + lane];
        s1 += redB[w * 256 + 64 + lane];
        s2 += redB[w * 256 + 128 + lane];
        s3 += redB[w * 256 + 192 + lane];
      }
      float ig = sigmoidf_(s0), fg = sigmoidf_(s1);
      float gv = tanhf(s2),     og = sigmoidf_(s3);
      creg = fg * creg + ig * gv;
      float hv = og * tanhf(creg);
      __hip_atomic_store(h_hist + ((size_t)(dir * SLEN + t) * BATCH + bB) * HID
                           + rk * 64 + lane,
                         hv, __ATOMIC_RELAXED, __HIP_MEMORY_SCOPE_AGENT);
      asm volatile("s_waitcnt vmcnt(0)" ::: "memory");
      if (lane == 0)
        __hip_atomic_store(flags + ((size_t)chB * SLEN + it) * 4 + rk, 1u,
                           __ATOMIC_RELAXED, __HIP_MEMORY_SCOPE_AGENT);
    } else if (tid < 256) {
      if (it < SLEN - 1) {
        if (pvA == 0) {                              // slow path: drift only
          const u32* fpA = flags + ((size_t)chA * SLEN + it) * 4 + wv;
          u32 v = aload(fpA); int sp = 0;
          while (v == 0 && ++sp < (1 << 14)) { __builtin_amdgcn_s_sleep(1); v = aload(fpA); }
        }
        asm volatile("" ::: "memory");
        u32 ha = aload((const u32*)(h_hist +
                   ((size_t)(dir * SLEN + t) * BATCH + bA) * HID) + tid);  // ISSUE
        asm volatile("" ::: "memory");               // keep hA above poll B
        const u32* fpB = flags + ((size_t)chB * SLEN + it) * 4 + wv;
        u32 v = aload(fpB); int sp = 0;
        while (v == 0 && ++sp < (1 << 14)) { __builtin_amdgcn_s_sleep(1); v = aload(fpB); }
        asm volatile("" ::: "memory");
        hwB = aload((const u32*)(h_hist +
                 ((size_t)(dir * SLEN + t) * BATCH + bB) * HID) + tid);    // ISSUE
        *(u32*)&vA[tid] = ha;                        // hA landed during poll B
      }
    } else if (wv < 6) {
      if (it < SLEN - 1) {
        vA[256 + ee] = evA;
        evA = embed[(size_t)xvA * EMB + ee];
        xvA = x[bA * SLEN + TS(it + 3)];
      }
    }
    bar();                                             // S4
  }
}

// ---------------------------------------------------------------------------
// feats[s][b][tag] = [hf|hb] . Wc[tag] + bc[tag]
// grid = (512/SB)*8 blocks (SB=16 timesteps, 8-batch chunk), 256 threads.
// Wc staged ONCE per block, reused for 16 timesteps.
// ---------------------------------------------------------------------------
__global__ __launch_bounds__(256) void feats_kernel(
    const float* __restrict__ h_hist, const float* __restrict__ Wc,
    const float* __restrict__ bc, float* __restrict__ feats)
{
  const int s0  = (blockIdx.x >> 3) * SB;
  const int b0  = (blockIdx.x & 7) * FB;
  const int tid = threadIdx.x;
  __shared__ float wc[NT * 516];    // 37.2 KB
  __shared__ float hl[FB * 516];    // 16.5 KB
  __shared__ float bcl[NT];
  if (tid < NT) bcl[tid] = bc[tid];
  for (int f = tid * 4; f < NT * 512; f += 1024) {
    float4 v = *(const float4*)(Wc + f);
    *(float4*)&wc[(f >> 9) * 516 + (f & 511)] = v;
  }
  for (int si = 0; si < SB; ++si) {
    const int s = s0 + si;
    const float* src0 = h_hist + ((size_t)s * BATCH + b0) * HID;
    const float* src1 = h_hist + ((size_t)(SLEN + s) * BATCH + b0) * HID;
    for (int f = tid * 4; f < FB * 256; f += 1024) {
      int b = f >> 8, j = f & 255;
      *(float4*)&hl[b * 516 + j]       = *(const float4*)(src0 + f);
      *(float4*)&hl[b * 516 + 256 + j] = *(const float4*)(src1 + f);
    }
    __syncthreads();
    if (tid < FB * NT) {
      int b = tid / NT, tag = tid - b * NT;
      float a = bcl[tag];
      const float* hp = &hl[b * 516];
      const float* wp = &wc[tag * 516];
#pragma unroll 8
      for (int k = 0; k < 512; k += 4) {
        float4 h4 = *(const float4*)(hp + k);
        float4 w4 = *(const float4*)(wp + k);
        a = fmaf(h4.x, w4.x, a); a = fmaf(h4.y, w4.y, a);
        a = fmaf(h4.z, w4.z, a); a = fmaf(h4.w, w4.w, a);
      }
      feats[((size_t)s * BATCH + b0 + b) * NT + tag] = a;
    }
    __syncthreads();   // WAR guard before restaging hl
  }
}

// ---------------------------------------------------------------------------
// Viterbi + backtrace, one block per batch, 64 threads (1 wave).
// Whole per-batch feats panel (512x18 = 36.9 KB) bulk-staged into LDS up
// front (coalesced, IC-hot) -> main loop pure LDS/VALU. mask is monotone
// (arange < len by construction) so m_t == (t < len). Semantics identical
// to reference (exact add order, strict > first-max, masked bp=0, snapshot
// at t=len-1, decode[S-1]=pointer).
// ---------------------------------------------------------------------------
__global__ __launch_bounds__(64) void viterbi_kernel(
    const float* __restrict__ feats, const int* __restrict__ mask,
    const float* __restrict__ trans, float* __restrict__ out)
{
  const int b = blockIdx.x;
  const int lane = threadIdx.x;
  __shared__ float flds[SLEN * NT];        // 36.9 KB
  __shared__ float tr[NT][NT + 1];
  __shared__ float part[2][NT + 2];
  __shared__ float lastp[NT + 2];
  __shared__ unsigned char bp[SLEN][20];   // 10.2 KB
  __shared__ int len_s;

  for (int f = lane; f < SLEN * NT; f += 64) {
    int s = f / NT, tag = f - s * NT;
    flds[f] = feats[((size_t)s * BATCH + b) * NT + tag];
  }
  for (int f = lane; f < NT * NT; f += 64) tr[f / NT][f % NT] = trans[f];
  int m = 0;
#pragma unroll
  for (int i = 0; i < 8; ++i) m += mask[b * SLEN + lane * 8 + i];
  for (int off = 32; off; off >>= 1) m += __shfl_down(m, off);
  if (lane == 0) len_s = m;
  __syncthreads();
  const int len = len_s;

  if (lane < NT) part[0][lane] = flds[lane] + tr[16][lane];   // START=16
  __syncthreads();

  int cur = 0;
  for (int t = 1; t < SLEN; ++t) {
    if (lane < NT) {
      float fcur = flds[t * NT + lane];
      float best = -3.0e38f; int bf = 0;
#pragma unroll
      for (int from = 0; from < NT; ++from) {
        float v = (fcur + tr[from][lane]) + part[cur][from];  // exact ref order
        if (v > best) { best = v; bf = from; }
      }
      part[cur ^ 1][lane] = best;
      bp[t][lane] = (t < len) ? (unsigned char)bf : (unsigned char)0;
      if (t == len - 1) lastp[lane] = best;
    }
    cur ^= 1;
    __syncthreads();
  }

  if (lane == 0) {
    float best = -3.0e38f; int bf = 0;
    for (int from = 0; from < NT; ++from) {
      float v = lastp[from] + tr[from][17];      // END=17
      if (v > best) { best = v; bf = from; }
    }
    out[b] = best;                                // path_score
    int ptr = bf;
    out[BATCH + (size_t)b * SLEN + (SLEN - 1)] = (float)ptr;
    for (int i = SLEN - 2; i >= 0; --i) {
      int nw = (i == len - 1) ? bf : (int)bp[i + 1][ptr];
      out[BATCH + (size_t)b * SLEN + i] = (float)nw;
      ptr = nw;
    }
  }
}

// ---------------------------------------------------------------------------
extern "C" void kernel_launch(void* const* d_in, const int* in_sizes, int n_in,
                              void* d_out, int out_size, void* d_ws, size_t ws_size,
                              hipStream_t stream) {
  const int*   x      = (const int*)  d_in[0];
  const int*   mask   = (const int*)  d_in[1];
  const float* embed  = (const float*)d_in[2];
  const float* Wih_f  = (const float*)d_in[3];
  const float* Whh_f  = (const float*)d_in[4];
  const float* bih_f  = (const float*)d_in[5];
  const float* bhh_f  = (const float*)d_in[6];
  const float* Wih_b  = (const float*)d_in[7];
  const float* Whh_b  = (const float*)d_in[8];
  const float* bih_b  = (const float*)d_in[9];
  const float* bhh_b  = (const float*)d_in[10];
  const float* Wc     = (const float*)d_in[11];
  const float* bc     = (const float*)d_in[12];
  const float* trans  = (const float*)d_in[13];
  const float* h0     = (const float*)d_in[14];
  const float* c0     = (const float*)d_in[15];
  float* out = (float*)d_out;

  // ws layout: h_hist @0 (64MB); flags and feats SHARE ws+64MB (disjoint in
  // time; flags re-zeroed each launch -> graph-replay deterministic).
  char* ws = (char*)d_ws;
  float* h_hist = (float*)ws;                                 // 64 MB
  u32*   flags  = (u32*)(ws + (size_t)67108864);              // 1 MB
  float* feats  = (float*)(ws + (size_t)67108864);            // 2.25 MB (aliases flags)

  hipMemsetAsync(flags, 0, (size_t)NCHAIN * SLEN * 4 * sizeof(u32), stream);
  lstm_kernel<<<256, 512, 0, stream>>>(x, embed, Wih_f, Whh_f, bih_f, bhh_f,
                                       Wih_b, Whh_b, bih_b, bhh_b, h0, c0,
                                       h_hist, flags);
  feats_kernel<<<(SLEN / SB) * 8, 256, 0, stream>>>(h_hist, Wc, bc, feats);
  viterbi_kernel<<<BATCH, 64, 0, stream>>>(feats, mask, trans, out);
}